// Round 2
// baseline (681.472 us; speedup 1.0000x reference)
//
#include <hip/hip_runtime.h>
#include <hip/hip_bf16.h>
#include <math.h>

// MultiLayerGRUParallel: B=32, S=4096, H=128, OUT=128, L=3
// Fused pipeline (6 launches):
//   prep0c (layer-0 prep + weight convert) -> kb(l0->l1) -> kb(l1->l2)
//   -> scan3v2 -> outmm -> outred
// KEY CHANGE vs prior: producers store L = inclusive LOCAL time-cumlae(u)
// (in the old "u" buffer) instead of raw u. Consumers then compute
// h_i = sigm(exp(A_i + lae(carry, L_i))) fully in PARALLEL (no 32-deep
// serial lae chain). The serial scan moves to producer epilogues as
// depth-4 runs + 4-wave LDS seg-total fixup (1 extra barrier/tile).
#define B_   32
#define S_   4096
#define H_   128
#define OUT_ 128
#define P_   (B_*S_)       // 131072 positions
#define NC_  64            // time chunks per chain
#define CH_  (S_/NC_)      // 64 steps per chunk
#define NKS_ 1024          // split-K workgroups for final matmul (4 blk/CU)
#define KTOT_ (H_*S_)      // 524288
#define NEGINF_ (-__builtin_inff())
#define HTP_ 136           // hT row pitch (ushorts): 272B -> row bank rotates by 4
#define LOGHALF_ (-0.6931471805599453f)

typedef __bf16 bf16x8 __attribute__((ext_vector_type(8)));
typedef float  f32x4  __attribute__((ext_vector_type(4)));
typedef unsigned short ushort8_t __attribute__((ext_vector_type(8)));

// ---- fast math (|args| bounded <~10 in this net; tolerance 5.2e-2) ----
__device__ __forceinline__ float sp_(float x) {            // softplus
  return __logf(1.f + __expf(x));
}
__device__ __forceinline__ float logg_(float x) {          // _log_g
  float t = (x >= 0.f) ? (x + 0.5f) : __builtin_amdgcn_rcpf(1.f + __expf(-x));
  return __logf(t);
}
__device__ __forceinline__ float lae_(float a, float b) {  // logaddexp
  float m = fmaxf(a, b);
  float d = -fabsf(a - b);                 // lae(-inf,x)=x fine
  return m + __logf(1.f + __expf(d));
}
__device__ __forceinline__ float sigm_(float e) {          // sigmoid
  return __builtin_amdgcn_rcpf(1.f + __expf(-e));
}
__device__ __forceinline__ unsigned short f2bf_(float f) { // fp32->bf16 RNE
  unsigned int u = __float_as_uint(f);
  u += 0x7fffu + ((u >> 16) & 1u);
  return (unsigned short)(u >> 16);
}

// DPP inclusive add-scan over 64 lanes: 6 VALU ops, no LDS pipe.
#define DPPADD_(v, ctrl, rmask) \
  ((v) + __int_as_float(__builtin_amdgcn_update_dpp( \
      0, __float_as_int(v), (ctrl), (rmask), 0xf, true)))
__device__ __forceinline__ float wscan_(float v) {
  v = DPPADD_(v, 0x111, 0xf);  // row_shr:1
  v = DPPADD_(v, 0x112, 0xf);  // row_shr:2
  v = DPPADD_(v, 0x114, 0xf);  // row_shr:4
  v = DPPADD_(v, 0x118, 0xf);  // row_shr:8
  v = DPPADD_(v, 0x142, 0xa);  // row_bcast:15 -> rows 1,3
  v = DPPADD_(v, 0x143, 0xc);  // row_bcast:31 -> rows 2,3
  return v;
}

// ---------------- layer 0 prep + chunk totals (+ weight convert tail) -------
// blocks [0,2048): one chunk each; wave w owns CONTIGUOUS positions
// [16w, 16w+16). Stores A and L (= local inclusive cumlae of u). One barrier
// for the 4-wave seg-total fixup.
// blocks [2048,2176): convert [Wz;Wh] of layers 1,2 to bf16 256x128.
__global__ __launch_bounds__(256) void prep0c_kernel(
    const float* __restrict__ x,
    const float* __restrict__ Wz, const float* __restrict__ bz,
    const float* __restrict__ Wh, const float* __restrict__ bh,
    float* __restrict__ Lb, float* __restrict__ A, float* __restrict__ tot,
    const float* __restrict__ Wz1, const float* __restrict__ Wh1,
    const float* __restrict__ Wz2, const float* __restrict__ Wh2,
    unsigned short* __restrict__ Wc1, unsigned short* __restrict__ Wc2)
{
  __shared__ float segw[4][128];
  if (blockIdx.x >= 2048) {            // weight-convert tail blocks
    int idx = (blockIdx.x - 2048) * 256 + threadIdx.x;  // < 32768
    Wc1[idx] = f2bf_(idx < 16384 ? Wz1[idx] : Wh1[idx - 16384]);
    Wc2[idx] = f2bf_(idx < 16384 ? Wz2[idx] : Wh2[idx - 16384]);
    return;
  }
  int lane = threadIdx.x & 63, w = threadIdx.x >> 6;
  float wz0 = Wz[lane], wz1 = Wz[lane + 64];
  float bz0 = bz[lane], bz1 = bz[lane + 64];
  float wh0 = Wh[lane], wh1 = Wh[lane + 64];
  float bh0 = bh[lane], bh1 = bh[lane + 64];
  int blk = blockIdx.x;                       // b*NC + c
  size_t base = (size_t)blk * (CH_ * H_);
  int pos0 = blk * CH_ + w * 16;
  float xv[16];
  #pragma unroll
  for (int j = 0; j < 16; ++j) xv[j] = x[pos0 + j];
  float L0[16], L1[16];
  float r0 = NEGINF_, r1 = NEGINF_;
  #pragma unroll
  for (int j = 0; j < 16; ++j) {
    float k0 = fmaf(xv[j], wz0, bz0), k1 = fmaf(xv[j], wz1, bz1);
    float g0 = fmaf(xv[j], wh0, bh0), g1 = fmaf(xv[j], wh1, bh1);
    float lc0 = -sp_(k0), lc1 = -sp_(k1);
    float lv0 = k0 + lc0 + logg_(g0);   // -sp(-k) == k - sp(k)
    float lv1 = k1 + lc1 + logg_(g1);
    float s0 = wscan_(lc0);
    float c0 = __shfl(s0, 63, 64);
    float s1 = wscan_(lc1) + c0;
    float u0 = lv0 - s0, u1 = lv1 - s1;
    r0 = lae_(r0, u0); r1 = lae_(r1, u1);
    L0[j] = r0; L1[j] = r1;
    size_t o = base + (size_t)(w * 16 + j) * H_;
    A[o + lane] = s0; A[o + 64 + lane] = s1;
  }
  segw[w][lane] = r0; segw[w][lane + 64] = r1;
  __syncthreads();
  float p0 = NEGINF_, p1 = NEGINF_;
  for (int jj = 0; jj < w; ++jj) {
    p0 = lae_(p0, segw[jj][lane]);
    p1 = lae_(p1, segw[jj][lane + 64]);
  }
  #pragma unroll
  for (int j = 0; j < 16; ++j) {
    size_t o = base + (size_t)(w * 16 + j) * H_;
    Lb[o + lane]      = lae_(p0, L0[j]);
    Lb[o + 64 + lane] = lae_(p1, L1[j]);
  }
  if (w == 0) {
    float q0 = lae_(lae_(segw[0][lane], segw[1][lane]),
                    lae_(segw[2][lane], segw[3][lane]));
    float q1 = lae_(lae_(segw[0][lane + 64], segw[1][lane + 64]),
                    lae_(segw[2][lane + 64], segw[3][lane + 64]));
    tot[(size_t)blk * H_ + lane] = q0;
    tot[(size_t)blk * H_ + 64 + lane] = q1;
  }
}

// ---------------- fused: carry + h(layer l) + matmul xW(l+1) + epilogue -----
// block = one chunk; 256 thr = 4 waves.
// Carry preamble -> r. Phase 1: FULLY PARALLEL h = sigm(exp(A + lae(r, L)))
// into hT (bf16, LDS). Phase 2/3 per 16-row m-tile: MFMA -> epilogue computes
// u, A(=channel wscan), local depth-4 time-cumlae per wave (contiguous rows
// 4w..4w+3), 4-wave seg fixup via LDS -> stores L, A for layer l+1.
__global__ __launch_bounds__(256) void kb_kernel(
    const float* __restrict__ totIn,          // layer l chunk totals
    const unsigned short* __restrict__ Wc,    // layer l+1 [256][128] bf16
    const float* __restrict__ bz, const float* __restrict__ bh,
    float* __restrict__ Lb, float* __restrict__ A,  // in: layer l, out: layer l+1
    float* __restrict__ totOut)               // out: layer l+1 chunk totals
{
  __shared__ unsigned short hT[64][HTP_]; // 17.0 KB h of layer l (bf16), padded
  __shared__ float kg[16][260];           // 16.25 KB one 16-row m-tile of [k|g]
  __shared__ float segw[4][128];          // carry partials / seg totals
  int tid = threadIdx.x;
  int lane = tid & 63, w = tid >> 6;
  int l15 = lane & 15, quad = lane >> 4;
  int half = tid >> 7, ch = tid & 127;
  int blk = blockIdx.x;
  int cidx = blk & (NC_ - 1);             // chunk index within its chain
  size_t base = (size_t)blk * (CH_ * H_);

  // ---- carry preamble: reduce tot[chain, 0..cidx-1, ch] ----
  {
    const float* tp = totIn + (size_t)(blk - cidx) * H_ + ch;
    float p0 = NEGINF_, p1 = NEGINF_;
    int i = half;
    for (; i + 2 < cidx; i += 4) {
      float a0 = tp[(size_t)i * H_];
      float a1 = tp[(size_t)(i + 2) * H_];
      p0 = lae_(p0, a0); p1 = lae_(p1, a1);
    }
    for (; i < cidx; i += 2) p0 = lae_(p0, tp[(size_t)i * H_]);
    segw[half * 2][ch] = p0; segw[half * 2 + 1][ch] = p1;
  }
  __syncthreads();

  // ---- phase 1: parallel h-compute (thread: channel ch, 32 positions) ----
  {
    float r = LOGHALF_;
    r = lae_(r, segw[0][ch]); r = lae_(r, segw[1][ch]);
    r = lae_(r, segw[2][ch]); r = lae_(r, segw[3][ch]);
    const float* Lp = Lb + base + (size_t)half * 32 * H_ + ch;
    const float* Ap = A  + base + (size_t)half * 32 * H_ + ch;
    for (int i0 = 0; i0 < 32; i0 += 16) {
      float Lv[16], Av[16];
      #pragma unroll
      for (int i = 0; i < 16; ++i) { Lv[i] = Lp[(i0 + i) * H_]; Av[i] = Ap[(i0 + i) * H_]; }
      #pragma unroll
      for (int i = 0; i < 16; ++i) {
        hT[half * 32 + i0 + i][ch] = f2bf_(sigm_(__expf(Av[i] + lae_(r, Lv[i]))));
      }
    }
  }
  __syncthreads();

  float bz0v = bz[lane], bz1v = bz[lane + 64];
  float bh0v = bh[lane], bh1v = bh[lane + 64];
  float R0 = NEGINF_, R1 = NEGINF_;       // running chunk prefix (per channel)

  // ---- phase 2/3 per 16-row m-tile: MFMA then epilogue ----
  // wave w owns output cols [64w, 64w+64) of N=256 ([k|g]) in the MFMA,
  // and CONTIGUOUS rows [4w, 4w+4) of the m-tile in the epilogue.
  for (int t = 0; t < 4; ++t) {
    f32x4 z = {0.f, 0.f, 0.f, 0.f};
    f32x4 acc[4] = {z, z, z, z};
    #pragma unroll
    for (int kk = 0; kk < 4; ++kk) {
      bf16x8 a = *reinterpret_cast<const bf16x8*>(&hT[t * 16 + l15][kk * 32 + quad * 8]);
      #pragma unroll
      for (int nt = 0; nt < 4; ++nt) {
        int n = w * 64 + nt * 16 + l15;
        bf16x8 bf = *reinterpret_cast<const bf16x8*>(Wc + n * 128 + kk * 32 + quad * 8);
        acc[nt] = __builtin_amdgcn_mfma_f32_16x16x32_bf16(a, bf, acc[nt], 0, 0, 0);
      }
    }
    __syncthreads();  // previous epilogue done reading kg/segw
    #pragma unroll
    for (int nt = 0; nt < 4; ++nt) {
      int col = w * 64 + nt * 16 + l15;
      #pragma unroll
      for (int r2 = 0; r2 < 4; ++r2)
        kg[quad * 4 + r2][col] = acc[nt][r2];   // D: row=quad*4+r2, col=l15
    }
    __syncthreads();
    float ll0[4], ll1[4];
    float lr0 = NEGINF_, lr1 = NEGINF_;
    #pragma unroll
    for (int i = 0; i < 4; ++i) {
      int row = w * 4 + i;            // contiguous rows per wave
      int sIdx = t * 16 + row;
      float k0 = kg[row][lane]        + bz0v;
      float k1 = kg[row][64 + lane]   + bz1v;
      float g0 = kg[row][128 + lane]  + bh0v;
      float g1 = kg[row][192 + lane]  + bh1v;
      float lc0 = -sp_(k0), lc1 = -sp_(k1);
      float lv0 = k0 + lc0 + logg_(g0);
      float lv1 = k1 + lc1 + logg_(g1);
      float s0 = wscan_(lc0);
      float c0 = __shfl(s0, 63, 64);
      float s1 = wscan_(lc1) + c0;
      float u0 = lv0 - s0, u1 = lv1 - s1;
      lr0 = lae_(lr0, u0); lr1 = lae_(lr1, u1);
      ll0[i] = lr0; ll1[i] = lr1;
      size_t o = base + (size_t)sIdx * H_;
      A[o + lane] = s0;  A[o + 64 + lane] = s1;
    }
    segw[w][lane] = lr0; segw[w][lane + 64] = lr1;
    __syncthreads();
    float p0 = R0, p1 = R1;
    for (int jj = 0; jj < w; ++jj) {
      p0 = lae_(p0, segw[jj][lane]);
      p1 = lae_(p1, segw[jj][lane + 64]);
    }
    #pragma unroll
    for (int i = 0; i < 4; ++i) {
      size_t o = base + (size_t)(t * 16 + w * 4 + i) * H_;
      Lb[o + lane]      = lae_(p0, ll0[i]);
      Lb[o + 64 + lane] = lae_(p1, ll1[i]);
    }
    R0 = lae_(R0, lae_(lae_(segw[0][lane], segw[1][lane]),
                       lae_(segw[2][lane], segw[3][lane])));
    R1 = lae_(R1, lae_(lae_(segw[0][lane + 64], segw[1][lane + 64]),
                       lae_(segw[2][lane + 64], segw[3][lane + 64])));
  }

  // ---- chunk totals = full prefix R (identical across waves) ----
  if (w == 0) {
    totOut[(size_t)blk * H_ + lane] = R0;
    totOut[(size_t)blk * H_ + 64 + lane] = R1;
  }
}

// ---------------- layer 2 final: parallel h -> hbf (bf16) -------------------
__global__ __launch_bounds__(256) void scan3v2_kernel(
    const float* __restrict__ Lb, const float* __restrict__ A,
    const float* __restrict__ totIn, unsigned short* __restrict__ hbf)
{
  __shared__ float tpart[4][128];
  int tid = threadIdx.x;
  int half = tid >> 7, ch = tid & 127;
  int blk = blockIdx.x;
  int cidx = blk & (NC_ - 1);
  size_t base = (size_t)blk * (CH_ * H_);

  // ---- carry preamble ----
  {
    const float* tp = totIn + (size_t)(blk - cidx) * H_ + ch;
    float p0 = NEGINF_, p1 = NEGINF_;
    int i = half;
    for (; i + 2 < cidx; i += 4) {
      float a0 = tp[(size_t)i * H_];
      float a1 = tp[(size_t)(i + 2) * H_];
      p0 = lae_(p0, a0); p1 = lae_(p1, a1);
    }
    for (; i < cidx; i += 2) p0 = lae_(p0, tp[(size_t)i * H_]);
    tpart[half * 2][ch] = p0; tpart[half * 2 + 1][ch] = p1;
  }
  __syncthreads();

  float r = LOGHALF_;
  r = lae_(r, tpart[0][ch]); r = lae_(r, tpart[1][ch]);
  r = lae_(r, tpart[2][ch]); r = lae_(r, tpart[3][ch]);
  const float* Lp = Lb + base + (size_t)half * 32 * H_ + ch;
  const float* Ap = A  + base + (size_t)half * 32 * H_ + ch;
  unsigned short* hp = hbf + base + (size_t)half * 32 * H_ + ch;
  for (int i0 = 0; i0 < 32; i0 += 16) {
    float Lv[16], Av[16];
    #pragma unroll
    for (int i = 0; i < 16; ++i) { Lv[i] = Lp[(i0 + i) * H_]; Av[i] = Ap[(i0 + i) * H_]; }
    #pragma unroll
    for (int i = 0; i < 16; ++i) {
      hp[(size_t)(i0 + i) * H_] = f2bf_(sigm_(__expf(Av[i] + lae_(r, Lv[i]))));
    }
  }
}

// ---------------- final matmul: out[32,128] = h2flat @ Wout^T + bout --------
__global__ __launch_bounds__(256) void outmm_kernel(
    const unsigned short* __restrict__ hbf,  // 32 x 524288 bf16
    const float* __restrict__ Wout,          // 128 x 524288 fp32
    float* __restrict__ part)
{
  const int KSL = KTOT_ / NKS_;  // 512
  int tid = threadIdx.x, w = tid >> 6, lane = tid & 63;
  int l15 = lane & 15, quad = lane >> 4;
  int k0base = blockIdx.x * KSL;
  f32x4 acc[2][2] = {{{0,0,0,0},{0,0,0,0}},{{0,0,0,0},{0,0,0,0}}};
  for (int ks = 0; ks < KSL; ks += 32) {
    int k0 = k0base + ks;
    bf16x8 a0 = *reinterpret_cast<const bf16x8*>(
        hbf + (size_t)l15 * KTOT_ + k0 + quad * 8);
    bf16x8 a1 = *reinterpret_cast<const bf16x8*>(
        hbf + (size_t)(16 + l15) * KTOT_ + k0 + quad * 8);
    #pragma unroll
    for (int nt = 0; nt < 2; ++nt) {
      int n = w * 32 + nt * 16 + l15;
      const float* wp = Wout + (size_t)n * KTOT_ + k0 + quad * 8;
      float4 wa = *reinterpret_cast<const float4*>(wp);
      float4 wb = *reinterpret_cast<const float4*>(wp + 4);
      ushort8_t tt;
      tt[0] = f2bf_(wa.x); tt[1] = f2bf_(wa.y); tt[2] = f2bf_(wa.z); tt[3] = f2bf_(wa.w);
      tt[4] = f2bf_(wb.x); tt[5] = f2bf_(wb.y); tt[6] = f2bf_(wb.z); tt[7] = f2bf_(wb.w);
      bf16x8 bf = __builtin_bit_cast(bf16x8, tt);
      acc[0][nt] = __builtin_amdgcn_mfma_f32_16x16x32_bf16(a0, bf, acc[0][nt], 0, 0, 0);
      acc[1][nt] = __builtin_amdgcn_mfma_f32_16x16x32_bf16(a1, bf, acc[1][nt], 0, 0, 0);
    }
  }
  float* pp = part + (size_t)blockIdx.x * (B_ * OUT_);
  #pragma unroll
  for (int mt = 0; mt < 2; ++mt)
    #pragma unroll
    for (int nt = 0; nt < 2; ++nt)
      #pragma unroll
      for (int r = 0; r < 4; ++r) {
        int b = mt * 16 + quad * 4 + r;
        int o = w * 32 + nt * 16 + l15;
        pp[b * OUT_ + o] = acc[mt][nt][r];
      }
}

// 4 outputs per block (one per wave); lanes stride the 1024 partials.
__global__ __launch_bounds__(256) void outred_kernel(
    const float* __restrict__ part, const float* __restrict__ bout,
    float* __restrict__ out)
{
  int w = threadIdx.x >> 6, lane = threadIdx.x & 63;
  int idx = blockIdx.x * 4 + w;  // < 4096
  float s = 0.f;
  for (int wg = lane; wg < NKS_; wg += 64) s += part[(size_t)wg * (B_ * OUT_) + idx];
  #pragma unroll
  for (int d = 32; d; d >>= 1) s += __shfl_down(s, (unsigned)d, 64);
  if (lane == 0) out[idx] = s + bout[idx & (OUT_ - 1)];
}

// ---------------- host launcher ----------------
extern "C" void kernel_launch(void* const* d_in, const int* in_sizes, int n_in,
                              void* d_out, int out_size, void* d_ws, size_t ws_size,
                              hipStream_t stream)
{
  const float* x    = (const float*)d_in[0];
  const float* Wz[3] = {(const float*)d_in[1], (const float*)d_in[5], (const float*)d_in[9]};
  const float* bz[3] = {(const float*)d_in[2], (const float*)d_in[6], (const float*)d_in[10]};
  const float* Wh[3] = {(const float*)d_in[3], (const float*)d_in[7], (const float*)d_in[11]};
  const float* bh[3] = {(const float*)d_in[4], (const float*)d_in[8], (const float*)d_in[12]};
  const float* Wout = (const float*)d_in[13];
  const float* bout = (const float*)d_in[14];
  float* out = (float*)d_out;

  char* ws = (char*)d_ws;
  float*          Lb    = (float*)(ws + 0);                  // 64 MiB (prefix L)
  float*          A     = (float*)(ws + 67108864);           // 64 MiB
  unsigned short* hbf   = (unsigned short*)(ws + 134217728); // 32 MiB
  unsigned short* Wc1   = (unsigned short*)(ws + 167772160); // 64 KiB
  unsigned short* Wc2   = (unsigned short*)(ws + 167837696); // 64 KiB
  float*          totA  = (float*)(ws + 167903232);          // 1 MiB
  float*          totB  = (float*)(ws + 168951808);          // 1 MiB
  float*          part  = (float*)(ws + 0);                  // 16 MiB, aliases Lb
                                                             // (dead after scan3v2)

  // layer 0 prep + totals (+ weight convert in tail blocks)
  prep0c_kernel<<<B_ * NC_ + 128, 256, 0, stream>>>(
      x, Wz[0], bz[0], Wh[0], bh[0], Lb, A, totA,
      Wz[1], Wh[1], Wz[2], Wh[2], Wc1, Wc2);

  // layer 0 -> 1 fused, layer 1 -> 2 fused (tot ping-pongs A->B->A)
  kb_kernel<<<B_ * NC_, 256, 0, stream>>>(totA, Wc1, bz[1], bh[1], Lb, A, totB);
  kb_kernel<<<B_ * NC_, 256, 0, stream>>>(totB, Wc2, bz[2], bh[2], Lb, A, totA);

  // layer 2 final: parallel h -> hbf
  scan3v2_kernel<<<B_ * NC_, 256, 0, stream>>>(Lb, A, totA, hbf);

  // output head (part aliases Lb region, which is dead by now)
  outmm_kernel<<<NKS_, 256, 0, stream>>>(hbf, Wout, part);
  outred_kernel<<<(B_ * OUT_) / 4, 256, 0, stream>>>(part, bout, out);
}